// Round 1
// baseline (1488.825 us; speedup 1.0000x reference)
//
#include <hip/hip_runtime.h>
#include <cstdint>
#include <cstddef>

// GRU (reset_after=True), B=256 T=512 F=128 H=256, fp32 in/out.
// k0: pack kernel/rec_kernel to fp16 MFMA-fragment order + combined bias
// k1: MX = x@Wk + bias_in (+bias_rec for z,r cols), stored fp16 fragment-order (201 MB ws)
// k2: persistent recurrence, 16 blocks x 16 batch rows, R register-resident fp16.

typedef _Float16 half8 __attribute__((ext_vector_type(8)));
typedef float floatx4 __attribute__((ext_vector_type(4)));

#define RPACK_OFF   0           // 48*8*64*8 halves = 393216 B
#define WKPACK_OFF  393216      // 48*4*64*8 halves = 196608 B
#define BIASP_OFF   589824      // 768 f32 = 3072 B
#define MXP_OFF     1048576     // 512*16*8*3*64*16 B = 201326592 B

#if defined(__has_builtin)
#if __has_builtin(__builtin_amdgcn_rcpf)
#define RCPF(x) __builtin_amdgcn_rcpf(x)
#else
#define RCPF(x) (1.0f/(x))
#endif
#else
#define RCPF(x) (1.0f/(x))
#endif

__device__ __forceinline__ float fast_sig(float x) {
    return RCPF(1.0f + __expf(-x));
}
__device__ __forceinline__ float fast_tanh(float y) {
    float yc = fminf(15.0f, fmaxf(-15.0f, y));
    float e = __expf(-2.0f * yc);
    return (1.0f - e) * RCPF(1.0f + e);
}

__device__ __forceinline__ int jt_of(int w, int s) {
    // s=0,1: z tiles 2w,2w+1 | s=2,3: r tiles 16+2w,16+2w+1 | s=4,5: h tiles 32+2w,32+2w+1
    return (s < 2) ? (2 * w + s) : (s < 4) ? (16 + 2 * w + (s - 2)) : (32 + 2 * w + (s - 4));
}

// ---------------- kernel 0: pack weights ----------------
__global__ void k0_pack(const float* __restrict__ Wk, const float* __restrict__ Rk,
                        const float* __restrict__ bias, char* __restrict__ ws) {
    int tid = blockIdx.x * 256 + threadIdx.x;
    _Float16* Rp = (_Float16*)(ws + RPACK_OFF);
    _Float16* Wp = (_Float16*)(ws + WKPACK_OFF);
    float* bp = (float*)(ws + BIASP_OFF);
    if (tid < 24576) {              // Rpack: jt(48) x kt(8) x lane(64) x 8
        int l = tid & 63, kt = (tid >> 6) & 7, jt = tid >> 9;
        int col = jt * 16 + (l & 15);
        int k0 = kt * 32 + (l >> 4) * 8;
        half8 v;
#pragma unroll
        for (int i = 0; i < 8; ++i) v[i] = (_Float16)Rk[(k0 + i) * 768 + col];
        *(half8*)(Rp + (size_t)tid * 8) = v;
    } else if (tid < 36864) {       // Wkpack: jt(48) x kt(4) x lane(64) x 8
        int j = tid - 24576;
        int l = j & 63, kt = (j >> 6) & 3, jt = j >> 8;
        int col = jt * 16 + (l & 15);
        int k0 = kt * 32 + (l >> 4) * 8;
        half8 v;
#pragma unroll
        for (int i = 0; i < 8; ++i) v[i] = (_Float16)Wk[(k0 + i) * 768 + col];
        *(half8*)(Wp + (size_t)j * 8) = v;
    } else if (tid < 37632) {       // bias_pack: input_bias + (rec_bias for cols<512)
        int c = tid - 36864;
        bp[c] = bias[c] + (c < 512 ? bias[768 + c] : 0.0f);
    }
}

// ---------------- kernel 1: MX GEMM (t fixed, 32 batch rows per block) ----------------
__launch_bounds__(512, 2)
__global__ void k1_mx(const float* __restrict__ x, char* __restrict__ ws) {
    __shared__ __attribute__((aligned(16))) char xl[8192];  // 32 rows x 128 fp16, swizzled
    int bid = blockIdx.x;              // 4096 = 512 t * 8 row-pairs
    int t = bid >> 3, jp = bid & 7;
    int b0 = jp * 32;
    int tid = threadIdx.x;
    int l = tid & 63, w = tid >> 6;
    int l15 = l & 15, hi = l >> 4;
    const _Float16* Wp = (const _Float16*)(ws + WKPACK_OFF);
    const float* bp = (const float*)(ws + BIASP_OFF);
    _Float16* MXp = (_Float16*)(ws + MXP_OFF);

    {   // stage x tile -> fp16 LDS (swizzled): rows contiguous 512B -> coalesced
        int rid = tid >> 4, f8 = (tid & 15) * 8;
        const float* src = x + ((size_t)(b0 + rid) * 512 + (size_t)t) * 128 + f8;
        floatx4 v0 = *(const floatx4*)src;
        floatx4 v1 = *(const floatx4*)(src + 4);
        half8 h;
#pragma unroll
        for (int i = 0; i < 4; ++i) { h[i] = (_Float16)v0[i]; h[4 + i] = (_Float16)v1[i]; }
        int byte = (rid * 256 + f8 * 2) ^ ((rid & 7) << 4);
        *(half8*)(xl + byte) = h;
    }

    half8 wk[6][4];
    floatx4 acA[6], acB[6];
#pragma unroll
    for (int s = 0; s < 6; ++s) {
        int jt = jt_of(w, s);
#pragma unroll
        for (int kt = 0; kt < 4; ++kt)
            wk[s][kt] = *(const half8*)(Wp + ((size_t)(jt * 4 + kt) * 64 + l) * 8);
        float bv = bp[jt * 16 + l15];
        acA[s] = (floatx4){bv, bv, bv, bv};
        acB[s] = (floatx4){bv, bv, bv, bv};
    }
    __syncthreads();

    int hi16 = hi * 16;
#pragma unroll
    for (int kt = 0; kt < 4; ++kt) {
        int r0 = l15, r1 = 16 + l15;
        half8 a0 = *(const half8*)(xl + r0 * 256 + ((kt * 64 + hi16) ^ ((r0 & 7) << 4)));
        half8 a1 = *(const half8*)(xl + r1 * 256 + ((kt * 64 + hi16) ^ ((r1 & 7) << 4)));
#pragma unroll
        for (int s = 0; s < 6; ++s) {
            acA[s] = __builtin_amdgcn_mfma_f32_16x16x32_f16(a0, wk[s][kt], acA[s], 0, 0, 0);
            acB[s] = __builtin_amdgcn_mfma_f32_16x16x32_f16(a1, wk[s][kt], acB[s], 0, 0, 0);
        }
    }

    int g0 = (t * 16 + jp * 2) * 8 + w;    // row-group 0 ; group 1 is g0+8
#pragma unroll
    for (int i = 0; i < 3; ++i) {
        half8 h0, h1;
#pragma unroll
        for (int q = 0; q < 4; ++q) {
            h0[q] = (_Float16)acA[2 * i][q]; h0[4 + q] = (_Float16)acA[2 * i + 1][q];
            h1[q] = (_Float16)acB[2 * i][q]; h1[4 + q] = (_Float16)acB[2 * i + 1][q];
        }
        *(half8*)(MXp + ((size_t)(g0 * 3 + i) * 64 + l) * 8) = h0;
        *(half8*)(MXp + ((size_t)((g0 + 8) * 3 + i) * 64 + l) * 8) = h1;
    }
}

// ---------------- kernel 2: persistent recurrence ----------------
#define MFMA6(A, KT) do { \
    ac0 = __builtin_amdgcn_mfma_f32_16x16x32_f16((A), bf[0][KT], ac0, 0, 0, 0); \
    ac1 = __builtin_amdgcn_mfma_f32_16x16x32_f16((A), bf[1][KT], ac1, 0, 0, 0); \
    ac2 = __builtin_amdgcn_mfma_f32_16x16x32_f16((A), bf[2][KT], ac2, 0, 0, 0); \
    ac3 = __builtin_amdgcn_mfma_f32_16x16x32_f16((A), bf[3][KT], ac3, 0, 0, 0); \
    ac4 = __builtin_amdgcn_mfma_f32_16x16x32_f16((A), bf[4][KT], ac4, 0, 0, 0); \
    ac5 = __builtin_amdgcn_mfma_f32_16x16x32_f16((A), bf[5][KT], ac5, 0, 0, 0); \
} while (0)

__launch_bounds__(512, 2)
__global__ void k2_rec(const float* __restrict__ biasraw, const char* __restrict__ ws,
                       float* __restrict__ out) {
    __shared__ __attribute__((aligned(16))) char hl[8192];  // h: 16 rows x 256 fp16, swizzled
    int nb = blockIdx.x;               // 16 blocks, rows [16nb,16nb+16)
    int tid = threadIdx.x;
    int l = tid & 63, w = tid >> 6;
    int l15 = l & 15, hi = l >> 4;
    const _Float16* Rp = (const _Float16*)(ws + RPACK_OFF);

    // persistent R fragments: 6 tiles x 8 k-steps (192 VGPR)
    half8 bf[6][8];
#pragma unroll
    for (int s = 0; s < 6; ++s) {
        int jt = jt_of(w, s);
#pragma unroll
        for (int kt = 0; kt < 8; ++kt)
            bf[s][kt] = *(const half8*)(Rp + ((size_t)(jt * 8 + kt) * 64 + l) * 8);
    }
    float brh0 = biasraw[768 + 512 + 32 * w + l15];        // rec_bias h-group (inside r*(..))
    float brh1 = biasraw[768 + 512 + 32 * w + l15 + 16];

    *(floatx4*)(hl + tid * 16) = (floatx4){0.f, 0.f, 0.f, 0.f};  // h0 = 0
    float h0q[4] = {0.f, 0.f, 0.f, 0.f}, h1q[4] = {0.f, 0.f, 0.f, 0.f};

    const int arow512 = l15 * 512;
    const int asw = (l15 & 7) << 4;
    const int hi16 = hi * 16;
#define ARD(KT) (*(const half8*)(hl + arow512 + (((KT) * 64 + hi16) ^ asw)))

    const char* mxbase = (const char*)(ws + MXP_OFF) + (size_t)(nb * 8 + w) * 3072 + (size_t)l * 16;
    half8 m0 = *(const half8*)(mxbase);
    half8 m1 = *(const half8*)(mxbase + 1024);
    half8 m2 = *(const half8*)(mxbase + 2048);

    float* outp = out + (size_t)(nb * 16 + hi * 4) * 256 + 32 * w + l15;

    __syncthreads();

    for (int t = 0; t < 512; ++t) {
        const char* mxnext = mxbase + (size_t)(t < 511 ? t + 1 : t) * 393216;

        floatx4 ac0, ac1, ac2, ac3, ac4, ac5;
#pragma unroll
        for (int q = 0; q < 4; ++q) {
            ac0[q] = (float)m0[q];     ac1[q] = (float)m0[4 + q];
            ac2[q] = (float)m1[q];     ac3[q] = (float)m1[4 + q];
        }
        ac4 = (floatx4){brh0, brh0, brh0, brh0};
        ac5 = (floatx4){brh1, brh1, brh1, brh1};
        // prefetch next-step MX (z,r chunks) — consumed at next acc-init
        m0 = *(const half8*)(mxnext);
        m1 = *(const half8*)(mxnext + 1024);

        // mh += h @ R  (A from LDS, 4-deep read pipeline)
        half8 a0 = ARD(0), a1 = ARD(1), a2 = ARD(2), a3 = ARD(3);
        MFMA6(a0, 0); a0 = ARD(4);
        MFMA6(a1, 1); a1 = ARD(5);
        MFMA6(a2, 2); a2 = ARD(6);
        MFMA6(a3, 3); a3 = ARD(7);
        MFMA6(a0, 4);
        MFMA6(a1, 5);
        MFMA6(a2, 6);
        MFMA6(a3, 7);

        __syncthreads();   // all A-reads done before h_lds overwrite

        size_t tout = (size_t)t * 65536;
#pragma unroll
        for (int q = 0; q < 4; ++q) {
            float z0 = fast_sig(ac0[q]);
            float r0 = fast_sig(ac2[q]);
            float c0 = fast_tanh((float)m2[q] + r0 * ac4[q]);
            float hn0 = z0 * h0q[q] + (1.0f - z0) * c0;
            h0q[q] = hn0;
            float z1 = fast_sig(ac1[q]);
            float r1 = fast_sig(ac3[q]);
            float c1 = fast_tanh((float)m2[4 + q] + r1 * ac5[q]);
            float hn1 = z1 * h1q[q] + (1.0f - z1) * c1;
            h1q[q] = hn1;

            int row = 4 * hi + q;
            int sw = (row & 7) << 4;
            *(_Float16*)(hl + ((row * 512 + (32 * w + l15) * 2) ^ sw)) = (_Float16)hn0;
            *(_Float16*)(hl + ((row * 512 + (32 * w + 16 + l15) * 2) ^ sw)) = (_Float16)hn1;
            outp[tout + q * 256] = hn0;
            outp[tout + q * 256 + 16] = hn1;
        }
        // prefetch next-step MX h-chunk (consumed at next gating)
        m2 = *(const half8*)(mxnext + 2048);

        __syncthreads();   // h_lds writes visible before next step's reads
    }
#undef ARD
}

extern "C" void kernel_launch(void* const* d_in, const int* in_sizes, int n_in,
                              void* d_out, int out_size, void* d_ws, size_t ws_size,
                              hipStream_t stream) {
    const float* x    = (const float*)d_in[0];   // (256,512,128)
    const float* Wk   = (const float*)d_in[1];   // (128,768)
    const float* Rk   = (const float*)d_in[2];   // (256,768)
    const float* bias = (const float*)d_in[3];   // (2,768)
    float* out = (float*)d_out;                  // (512,256,256)
    char* ws = (char*)d_ws;                      // needs ~193 MiB

    k0_pack<<<147, 256, 0, stream>>>(Wk, Rk, bias, ws);
    k1_mx<<<4096, 512, 0, stream>>>(x, ws);
    k2_rec<<<16, 512, 0, stream>>>(bias, ws, out);
}